// Round 1
// baseline (186.376 us; speedup 1.0000x reference)
//
#include <hip/hip_runtime.h>

// Trilinear feature-grid interpolation.
// grid layout: [R][R][R][3] = [z][y][x][c], R=256.
// input: [N][3] = (x, y, z) per point, in [0,1).
__global__ __launch_bounds__(256) void fgrid3d_kernel(
        const float* __restrict__ inp,
        const float* __restrict__ grid,
        float* __restrict__ out,
        int n) {
    int i = blockIdx.x * blockDim.x + threadIdx.x;
    if (i >= n) return;

    const int R = 256;

    float px = inp[3 * i + 0];
    float py = inp[3 * i + 1];
    float pz = inp[3 * i + 2];

    float sx = px * 255.0f;
    float sy = py * 255.0f;
    float sz = pz * 255.0f;

    int xl = (int)floorf(sx); xl = xl < 0 ? 0 : (xl > 254 ? 254 : xl);
    int yl = (int)floorf(sy); yl = yl < 0 ? 0 : (yl > 254 ? 254 : yl);
    int zl = (int)floorf(sz); zl = zl < 0 ? 0 : (zl > 254 ? 254 : zl);

    float tx = sx - (float)xl;
    float ty = sy - (float)yl;
    float tz = sz - (float)zl;

    // Four row segments of 6 contiguous floats (two x-adjacent corners x 3 ch).
    int b00 = ((zl * R + yl) * R + xl) * 3; // (zl, yl)
    int b01 = b00 + R * 3;                  // (zl, yu)
    int b10 = b00 + R * R * 3;              // (zu, yl)
    int b11 = b10 + R * 3;                  // (zu, yu)

    float s00[6], s01[6], s10[6], s11[6];
#pragma unroll
    for (int k = 0; k < 6; ++k) s00[k] = grid[b00 + k];
#pragma unroll
    for (int k = 0; k < 6; ++k) s01[k] = grid[b01 + k];
#pragma unroll
    for (int k = 0; k < 6; ++k) s10[k] = grid[b10 + k];
#pragma unroll
    for (int k = 0; k < 6; ++k) s11[k] = grid[b11 + k];

    float o[3];
#pragma unroll
    for (int c = 0; c < 3; ++c) {
        float c00 = s00[c] * (1.0f - tx) + s00[c + 3] * tx;
        float c01 = s01[c] * (1.0f - tx) + s01[c + 3] * tx;
        float c10 = s10[c] * (1.0f - tx) + s10[c + 3] * tx;
        float c11 = s11[c] * (1.0f - tx) + s11[c + 3] * tx;
        float c0 = c00 * (1.0f - ty) + c01 * ty;
        float c1 = c10 * (1.0f - ty) + c11 * ty;
        o[c] = c0 * (1.0f - tz) + c1 * tz;
    }

    out[3 * i + 0] = o[0];
    out[3 * i + 1] = o[1];
    out[3 * i + 2] = o[2];
}

extern "C" void kernel_launch(void* const* d_in, const int* in_sizes, int n_in,
                              void* d_out, int out_size, void* d_ws, size_t ws_size,
                              hipStream_t stream) {
    const float* inp  = (const float*)d_in[0];  // [N][3]
    const float* grid = (const float*)d_in[1];  // [256][256][256][3]
    float* out = (float*)d_out;                 // [N][3]

    int n = in_sizes[0] / 3;
    int threads = 256;
    int blocks = (n + threads - 1) / threads;
    fgrid3d_kernel<<<blocks, threads, 0, stream>>>(inp, grid, out, n);
}